// Round 15
// baseline (144.376 us; speedup 1.0000x reference)
//
#include <hip/hip_runtime.h>
#include <hip/hip_fp16.h>

#define NN 50000
#define NE 800000
#define DD 64
#define NG 64

#define NBKT 196        // ceil(NN/256) coarse buckets (dst >> 8)
#define MAXB 5120       // padded tmp slots per bucket (mean 4082)
#define SRTQ 1792       // srt slots per (bucket, quarter): mean 1020 + 10 sigma + 448 pad
#define P1CH 2048       // edges per pass-1 block
#define P1NB ((NE + P1CH - 1) / P1CH)   // 391

// ---------------- pass 1: bin edges by dst>>8 into padded tmp buckets ----------------
__global__ __launch_bounds__(256) void bin_k(const int* __restrict__ ei,
                                             const float* __restrict__ ew,
                                             int* __restrict__ bucket_cnt,
                                             unsigned int* __restrict__ tmp_pay,
                                             unsigned char* __restrict__ tmp_c8) {
    __shared__ int hist[NBKT];
    __shared__ int basec[NBKT];
    const int t = threadIdx.x;
    const int e0 = blockIdx.x * P1CH;
    for (int i = t; i < NBKT; i += 256) hist[i] = 0;
    __syncthreads();
    int rr[8]; int cc[8]; float wwf[8];
    #pragma unroll
    for (int i = 0; i < 8; ++i) {
        int e = e0 + i * 256 + t;
        if (e < NE) {
            rr[i] = ei[e]; cc[i] = ei[NE + e]; wwf[i] = ew[e];
            atomicAdd(&hist[cc[i] >> 8], 1);
        } else cc[i] = -1;
    }
    __syncthreads();
    for (int i = t; i < NBKT; i += 256)
        basec[i] = (hist[i] > 0) ? (i * MAXB + atomicAdd(&bucket_cnt[i], hist[i])) : 0;
    __syncthreads();
    #pragma unroll
    for (int i = 0; i < 8; ++i) {
        if (cc[i] >= 0) {
            int b = cc[i] >> 8;
            int slot = atomicAdd(&basec[b], 1);   // LDS cursor within reservation
            unsigned int hb = (unsigned int)__half_as_ushort(__float2half(wwf[i]));
            tmp_pay[slot] = (hb << 16) | (unsigned int)rr[i];
            tmp_c8[slot] = (unsigned char)(cc[i] & 255);
        }
    }
}

// ---------------- pass 2: per-(bucket,quarter) sort + per-node (start,pcnt) + dis ----
// 4 blocks per bucket; each handles 64 nodes, reading all bucket edges and placing
// only its quarter into its own srt window [bq*SRTQ, (bq+1)*SRTQ).
__global__ __launch_bounds__(256) void build_k(const int* __restrict__ bucket_cnt,
                                               const unsigned int* __restrict__ tmp_pay,
                                               const unsigned char* __restrict__ tmp_c8,
                                               unsigned int* __restrict__ srt,
                                               int2* __restrict__ rowse,
                                               float* __restrict__ dis) {
    __shared__ int hist[64];
    __shared__ int cursor[64];
    __shared__ float degf[64];
    const int bq = blockIdx.x;
    const int b = bq >> 2, q = bq & 3;
    const int t = threadIdx.x;
    const int cntb = bucket_cnt[b];
    const int tbase = b * MAXB;
    if (t < 64) { hist[t] = 0; degf[t] = 0.0f; }
    __syncthreads();
    for (int i = t; i < cntb; i += 256) {
        int c8 = tmp_c8[tbase + i];
        if ((c8 >> 6) == q) atomicAdd(&hist[c8 & 63], 1);
    }
    __syncthreads();
    int v = 0, pv = 0, excl = 0;
    if (t < 64) {   // 1-wave exclusive scan of padded counts
        v = hist[t];
        pv = (v + 7) & ~7;
        int pre = pv;
        #pragma unroll
        for (int off = 1; off < 64; off <<= 1) {
            int u = __shfl_up(pre, off);
            if (t >= off) pre += u;
        }
        excl = bq * SRTQ + pre - pv;
        cursor[t] = excl;
    }
    __syncthreads();
    for (int i = t; i < cntb; i += 256) {
        int c8 = tmp_c8[tbase + i];
        if ((c8 >> 6) == q) {
            unsigned int u = tmp_pay[tbase + i];
            int slot = atomicAdd(&cursor[c8 & 63], 1);   // LDS
            srt[slot] = u;
            float w = __half2float(__ushort_as_half((unsigned short)(u >> 16)));
            atomicAdd(&degf[c8 & 63], w);                // LDS fp32
        }
    }
    __syncthreads();
    if (t < 64) {
        for (int i = excl + v; i < excl + pv; ++i) srt[i] = 0u;  // dummy pad edges
        const int node = b * 256 + q * 64 + t;
        if (node < NN) {
            rowse[node] = make_int2(excl, pv);
            dis[node] = rsqrtf(1.0f + degf[t]);
        }
    }
}

// ---------------- GEMM: A' = (act(X) @ W) * dis[row], fp16 out ----------------
template<bool ACT, typename TIN>
__global__ __launch_bounds__(256, 4) void gemm_k(
    const TIN* __restrict__ X, const float* __restrict__ W,
    const float* __restrict__ bias_prev, const float* __restrict__ dis,
    __half* __restrict__ Ah)
{
    __shared__ float Ws[64][64];   // [k][j]
    __shared__ float Xs[64][68];   // [r][k], +4 pad
    const int t = threadIdx.x;
    const int row0 = blockIdx.x * 64;

    #pragma unroll
    for (int s = t; s < 64 * 64; s += 256) ((float*)Ws)[s] = W[s];
    #pragma unroll
    for (int s = t; s < 64 * 64; s += 256) {
        int r = s >> 6, k = s & 63;
        int row = row0 + r;
        if (row >= NN) row = NN - 1;
        float v = static_cast<float>(X[(size_t)row * DD + k]);
        if (ACT) v = fmaxf(v + bias_prev[k], 0.0f);
        Xs[r][k] = v;
    }
    __syncthreads();

    const int tc = t & 15;
    const int tr = t >> 4;
    float4 acc[4];
    #pragma unroll
    for (int i = 0; i < 4; ++i) acc[i] = make_float4(0.f, 0.f, 0.f, 0.f);

    #pragma unroll 2
    for (int kc = 0; kc < 16; ++kc) {
        const int k = kc * 4;
        float4 w0 = *reinterpret_cast<const float4*>(&Ws[k + 0][tc * 4]);
        float4 w1 = *reinterpret_cast<const float4*>(&Ws[k + 1][tc * 4]);
        float4 w2 = *reinterpret_cast<const float4*>(&Ws[k + 2][tc * 4]);
        float4 w3 = *reinterpret_cast<const float4*>(&Ws[k + 3][tc * 4]);
        #pragma unroll
        for (int i = 0; i < 4; ++i) {
            float4 xv = *reinterpret_cast<const float4*>(&Xs[tr * 4 + i][k]);
            acc[i].x += xv.x * w0.x + xv.y * w1.x + xv.z * w2.x + xv.w * w3.x;
            acc[i].y += xv.x * w0.y + xv.y * w1.y + xv.z * w2.y + xv.w * w3.y;
            acc[i].z += xv.x * w0.z + xv.y * w1.z + xv.z * w2.z + xv.w * w3.z;
            acc[i].w += xv.x * w0.w + xv.y * w1.w + xv.z * w2.w + xv.w * w3.w;
        }
    }

    #pragma unroll
    for (int i = 0; i < 4; ++i) {
        int row = row0 + tr * 4 + i;
        if (row >= NN) break;
        float d = dis[row];
        __half2 h0 = __floats2half2_rn(acc[i].x * d, acc[i].y * d);
        __half2 h1 = __floats2half2_rn(acc[i].z * d, acc[i].w * d);
        uint2 st;
        st.x = *reinterpret_cast<unsigned int*>(&h0);
        st.y = *reinterpret_cast<unsigned int*>(&h1);
        *reinterpret_cast<uint2*>(&Ah[(size_t)row * DD + tc * 4]) = st;
    }
}

// ---------------- gather: B[c] = dis[c] * (A'[c] + sum_e w_e * A'[r_e]), fp16 out ----
// One wave per node; halves split the edge stream. __half2 loads: one VMEM
// instruction covers two rows; 8 rows in flight per wave.
__global__ __launch_bounds__(256) void gather_k(
    const int2* __restrict__ rowse, const unsigned int* __restrict__ srt,
    const float* __restrict__ dis,
    const __half2* __restrict__ Ah2, __half* __restrict__ Bh)
{
    const int node = blockIdx.x * 4 + (threadIdx.x >> 6);
    const int wl = threadIdx.x & 63;
    const int h = wl >> 5;     // which half of each 8-edge block
    const int l = wl & 31;     // feature-pair index
    if (node >= NN) return;
    const int2 se = rowse[node];
    float ax0 = 0.f, ay0 = 0.f, ax1 = 0.f, ay1 = 0.f;
    if (h == 0) {              // self-loop term on half 0
        __half2 s = Ah2[(size_t)node * 32 + l];
        ax0 = __half2float(__low2half(s));
        ay0 = __half2float(__high2half(s));
    }
    const unsigned int* p = srt + se.x + h * 4;
    for (int n = se.y; n > 0; n -= 8, p += 8) {
        uint4 u = *reinterpret_cast<const uint4*>(p);   // this half's 4 edges
        __half2 a0 = Ah2[(size_t)(u.x & 0xffffu) * 32 + l];
        __half2 a1 = Ah2[(size_t)(u.y & 0xffffu) * 32 + l];
        __half2 a2 = Ah2[(size_t)(u.z & 0xffffu) * 32 + l];
        __half2 a3 = Ah2[(size_t)(u.w & 0xffffu) * 32 + l];
        float w0 = __half2float(__ushort_as_half((unsigned short)(u.x >> 16)));
        float w1 = __half2float(__ushort_as_half((unsigned short)(u.y >> 16)));
        float w2 = __half2float(__ushort_as_half((unsigned short)(u.z >> 16)));
        float w3 = __half2float(__ushort_as_half((unsigned short)(u.w >> 16)));
        ax0 += w0 * __half2float(__low2half(a0));
        ay0 += w0 * __half2float(__high2half(a0));
        ax1 += w1 * __half2float(__low2half(a1));
        ay1 += w1 * __half2float(__high2half(a1));
        ax0 += w2 * __half2float(__low2half(a2));
        ay0 += w2 * __half2float(__high2half(a2));
        ax1 += w3 * __half2float(__low2half(a3));
        ay1 += w3 * __half2float(__high2half(a3));
    }
    float ax = ax0 + ax1, ay = ay0 + ay1;
    ax += __shfl_xor(ax, 32);
    ay += __shfl_xor(ay, 32);
    if (h == 0) {
        float d = dis[node];
        __half2 hv = __floats2half2_rn(d * ax, d * ay);
        *reinterpret_cast<__half2*>(&Bh[(size_t)node * DD + 2 * l]) = hv;
    }
}

// ---------------- pooling: 32 rows per block, fp16 input ----------------
__global__ __launch_bounds__(64) void pool(
    const __half* __restrict__ Bh, const float* __restrict__ b2,
    const int* __restrict__ batch,
    float* __restrict__ sums, float* __restrict__ cnts, int n)
{
    const int lane = threadIdx.x;
    const int start = blockIdx.x * 32;
    const int end = min(start + 32, n);
    const float bb = b2[lane];
    float acc = 0.0f;
    int cn = 0;
    int curg = batch[start];
    for (int i = start; i < end; ++i) {
        int g = batch[i];
        if (g != curg) {
            unsafeAtomicAdd(&sums[curg * DD + lane], acc);
            if (lane == 0) unsafeAtomicAdd(&cnts[curg], (float)cn);
            acc = 0.0f; cn = 0; curg = g;
        }
        acc += fmaxf(__half2float(Bh[(size_t)i * DD + lane]) + bb, 0.0f);
        cn++;
    }
    if (cn > 0) {
        unsafeAtomicAdd(&sums[curg * DD + lane], acc);
        if (lane == 0) unsafeAtomicAdd(&cnts[curg], (float)cn);
    }
}

__global__ void finalize(const float* __restrict__ sums, const float* __restrict__ cnts,
                         float* __restrict__ out) {
    int i = blockIdx.x * blockDim.x + threadIdx.x;
    if (i < NG * DD) {
        int g = i >> 6;
        out[i] = sums[i] / fmaxf(cnts[g], 1.0f);
    }
}

// ---------------- host ----------------
extern "C" void kernel_launch(void* const* d_in, const int* in_sizes, int n_in,
                              void* d_out, int out_size, void* d_ws, size_t ws_size,
                              hipStream_t stream) {
    const float* x   = (const float*)d_in[0];
    const int*   ei  = (const int*)  d_in[1];
    const float* ew  = (const float*)d_in[2];
    const int*   bat = (const int*)  d_in[3];
    const float* W1  = (const float*)d_in[4];
    const float* b1  = (const float*)d_in[5];
    const float* W2  = (const float*)d_in[6];
    const float* b2  = (const float*)d_in[7];
    float* out = (float*)d_out;

    char* ws = (char*)d_ws;
    size_t off = 0;
    __half* Ah        = (__half*)(ws + off); off += (size_t)NN * DD * 2;            // 6.4 MB
    __half* Bh        = (__half*)(ws + off); off += (size_t)NN * DD * 2;            // 6.4 MB
    unsigned int* srt = (unsigned int*)(ws + off); off += (size_t)NBKT * 4 * SRTQ * 4; // 5.6 MB
    unsigned int* tmp_pay = (unsigned int*)(ws + off); off += (size_t)NBKT * MAXB * 4;  // 4.0 MB
    unsigned char* tmp_c8 = (unsigned char*)(ws + off); off += (size_t)NBKT * MAXB;     // 1.0 MB
    int2*   rowse      = (int2*)(ws + off); off += (size_t)NN * 8;
    float*  dis        = (float*)(ws + off); off += (size_t)NN * 4;
    // contiguous zero-init region: bucket_cnt | sums | cnts
    int*    bucket_cnt = (int*)  (ws + off); off += (size_t)NBKT * 4;
    float*  sums       = (float*)(ws + off); off += (size_t)NG * DD * 4;
    float*  cnts       = (float*)(ws + off); off += (size_t)NG * 4;

    (void)hipMemsetAsync(bucket_cnt, 0, (size_t)(NBKT + NG * DD + NG) * 4, stream);

    // CSR build (shared by both layers) — no per-edge global atomics
    bin_k<<<P1NB, 256, 0, stream>>>(ei, ew, bucket_cnt, tmp_pay, tmp_c8);
    build_k<<<NBKT * 4, 256, 0, stream>>>(bucket_cnt, tmp_pay, tmp_c8, srt, rowse, dis);

    // layer 1
    gemm_k<false, float><<<(NN + 63) / 64, 256, 0, stream>>>(x, W1, nullptr, dis, Ah);
    gather_k<<<(NN + 3) / 4, 256, 0, stream>>>(rowse, srt, dis, (const __half2*)Ah, Bh);

    // layer 2
    gemm_k<true, __half><<<(NN + 63) / 64, 256, 0, stream>>>(Bh, W2, b1, dis, Ah);
    gather_k<<<(NN + 3) / 4, 256, 0, stream>>>(rowse, srt, dis, (const __half2*)Ah, Bh);

    // pooling (bias+relu fused on read)
    pool<<<(NN + 31) / 32, 64, 0, stream>>>(Bh, b2, bat, sums, cnts, NN);
    finalize<<<(NG * DD + 255) / 256, 256, 0, stream>>>(sums, cnts, out);
}

// Round 16
// 143.532 us; speedup vs baseline: 1.0059x; 1.0059x over previous
//
#include <hip/hip_runtime.h>
#include <hip/hip_fp16.h>
#include <type_traits>

#define NN 50000
#define NE 800000
#define DD 64
#define NG 64

#define NBKT 196        // ceil(NN/256) coarse buckets (dst >> 8)
#define MAXB 5120       // padded tmp slots per bucket (mean 4082)
#define SRTQ 1792       // srt slots per (bucket, quarter)
#define P1CH 2048       // edges per pass-1 block
#define P1NB ((NE + P1CH - 1) / P1CH)   // 391

// ---------------- pass 1: bin edges by dst>>8 into padded tmp buckets ----------------
__global__ __launch_bounds__(256) void bin_k(const int* __restrict__ ei,
                                             const float* __restrict__ ew,
                                             int* __restrict__ bucket_cnt,
                                             unsigned int* __restrict__ tmp_pay,
                                             unsigned char* __restrict__ tmp_c8) {
    __shared__ int hist[NBKT];
    __shared__ int basec[NBKT];
    const int t = threadIdx.x;
    const int e0 = blockIdx.x * P1CH;
    for (int i = t; i < NBKT; i += 256) hist[i] = 0;
    __syncthreads();
    int rr[8]; int cc[8]; float wwf[8];
    #pragma unroll
    for (int i = 0; i < 8; ++i) {
        int e = e0 + i * 256 + t;
        if (e < NE) {
            rr[i] = ei[e]; cc[i] = ei[NE + e]; wwf[i] = ew[e];
            atomicAdd(&hist[cc[i] >> 8], 1);
        } else cc[i] = -1;
    }
    __syncthreads();
    for (int i = t; i < NBKT; i += 256)
        basec[i] = (hist[i] > 0) ? (i * MAXB + atomicAdd(&bucket_cnt[i], hist[i])) : 0;
    __syncthreads();
    #pragma unroll
    for (int i = 0; i < 8; ++i) {
        if (cc[i] >= 0) {
            int b = cc[i] >> 8;
            int slot = atomicAdd(&basec[b], 1);   // LDS cursor within reservation
            unsigned int hb = (unsigned int)__half_as_ushort(__float2half(wwf[i]));
            tmp_pay[slot] = (hb << 16) | (unsigned int)rr[i];
            tmp_c8[slot] = (unsigned char)(cc[i] & 255);
        }
    }
}

// ---------------- pass 2: per-(bucket,quarter) sort + per-node (start,pcnt) + dis ----
__global__ __launch_bounds__(256) void build_k(const int* __restrict__ bucket_cnt,
                                               const unsigned int* __restrict__ tmp_pay,
                                               const unsigned char* __restrict__ tmp_c8,
                                               unsigned int* __restrict__ srt,
                                               int2* __restrict__ rowse,
                                               float* __restrict__ dis) {
    __shared__ int hist[64];
    __shared__ int cursor[64];
    __shared__ float degf[64];
    const int bq = blockIdx.x;
    const int b = bq >> 2, q = bq & 3;
    const int t = threadIdx.x;
    const int cntb = bucket_cnt[b];
    const int tbase = b * MAXB;
    if (t < 64) { hist[t] = 0; degf[t] = 0.0f; }
    __syncthreads();
    for (int i = t; i < cntb; i += 256) {
        int c8 = tmp_c8[tbase + i];
        if ((c8 >> 6) == q) atomicAdd(&hist[c8 & 63], 1);
    }
    __syncthreads();
    int v = 0, pv = 0, excl = 0;
    if (t < 64) {   // 1-wave exclusive scan of padded counts
        v = hist[t];
        pv = (v + 7) & ~7;
        int pre = pv;
        #pragma unroll
        for (int off = 1; off < 64; off <<= 1) {
            int u = __shfl_up(pre, off);
            if (t >= off) pre += u;
        }
        excl = bq * SRTQ + pre - pv;
        cursor[t] = excl;
    }
    __syncthreads();
    for (int i = t; i < cntb; i += 256) {
        int c8 = tmp_c8[tbase + i];
        if ((c8 >> 6) == q) {
            unsigned int u = tmp_pay[tbase + i];
            int slot = atomicAdd(&cursor[c8 & 63], 1);   // LDS
            srt[slot] = u;
            float w = __half2float(__ushort_as_half((unsigned short)(u >> 16)));
            atomicAdd(&degf[c8 & 63], w);                // LDS fp32
        }
    }
    __syncthreads();
    if (t < 64) {
        for (int i = excl + v; i < excl + pv; ++i) srt[i] = 0u;  // dummy pad edges
        const int node = b * 256 + q * 64 + t;
        if (node < NN) {
            rowse[node] = make_int2(excl, pv);
            dis[node] = rsqrtf(1.0f + degf[t]);
        }
    }
}

// ---------------- GEMM: A' = (act(X) @ W) * dis[row], fp16 out ----------------
// fp16 input path stages with uint2 (4 halves / 8 B per load instruction).
template<bool ACT, typename TIN>
__global__ __launch_bounds__(256, 4) void gemm_k(
    const TIN* __restrict__ X, const float* __restrict__ W,
    const float* __restrict__ bias_prev, const float* __restrict__ dis,
    __half* __restrict__ Ah)
{
    __shared__ float Ws[64][64];   // [k][j]
    __shared__ float Xs[64][68];   // [r][k], +4 pad
    const int t = threadIdx.x;
    const int row0 = blockIdx.x * 64;

    #pragma unroll
    for (int s = t; s < 64 * 64; s += 256) ((float*)Ws)[s] = W[s];

    if constexpr (std::is_same<TIN, __half>::value) {
        #pragma unroll
        for (int s = t; s < 64 * 16; s += 256) {   // 4 halves per step
            int r = s >> 4, k4 = (s & 15) * 4;
            int row = row0 + r;
            if (row >= NN) row = NN - 1;
            uint2 u = *reinterpret_cast<const uint2*>(&X[(size_t)row * DD + k4]);
            __half2 p01 = *reinterpret_cast<const __half2*>(&u.x);
            __half2 p23 = *reinterpret_cast<const __half2*>(&u.y);
            float v0 = __half2float(__low2half(p01));
            float v1 = __half2float(__high2half(p01));
            float v2 = __half2float(__low2half(p23));
            float v3 = __half2float(__high2half(p23));
            if (ACT) {
                v0 = fmaxf(v0 + bias_prev[k4 + 0], 0.0f);
                v1 = fmaxf(v1 + bias_prev[k4 + 1], 0.0f);
                v2 = fmaxf(v2 + bias_prev[k4 + 2], 0.0f);
                v3 = fmaxf(v3 + bias_prev[k4 + 3], 0.0f);
            }
            Xs[r][k4 + 0] = v0; Xs[r][k4 + 1] = v1;
            Xs[r][k4 + 2] = v2; Xs[r][k4 + 3] = v3;
        }
    } else {
        #pragma unroll
        for (int s = t; s < 64 * 64; s += 256) {
            int r = s >> 6, k = s & 63;
            int row = row0 + r;
            if (row >= NN) row = NN - 1;
            float v = (float)X[(size_t)row * DD + k];
            if (ACT) v = fmaxf(v + bias_prev[k], 0.0f);
            Xs[r][k] = v;
        }
    }
    __syncthreads();

    const int tc = t & 15;
    const int tr = t >> 4;
    float4 acc[4];
    #pragma unroll
    for (int i = 0; i < 4; ++i) acc[i] = make_float4(0.f, 0.f, 0.f, 0.f);

    #pragma unroll 2
    for (int kc = 0; kc < 16; ++kc) {
        const int k = kc * 4;
        float4 w0 = *reinterpret_cast<const float4*>(&Ws[k + 0][tc * 4]);
        float4 w1 = *reinterpret_cast<const float4*>(&Ws[k + 1][tc * 4]);
        float4 w2 = *reinterpret_cast<const float4*>(&Ws[k + 2][tc * 4]);
        float4 w3 = *reinterpret_cast<const float4*>(&Ws[k + 3][tc * 4]);
        #pragma unroll
        for (int i = 0; i < 4; ++i) {
            float4 xv = *reinterpret_cast<const float4*>(&Xs[tr * 4 + i][k]);
            acc[i].x += xv.x * w0.x + xv.y * w1.x + xv.z * w2.x + xv.w * w3.x;
            acc[i].y += xv.x * w0.y + xv.y * w1.y + xv.z * w2.y + xv.w * w3.y;
            acc[i].z += xv.x * w0.z + xv.y * w1.z + xv.z * w2.z + xv.w * w3.z;
            acc[i].w += xv.x * w0.w + xv.y * w1.w + xv.z * w2.w + xv.w * w3.w;
        }
    }

    #pragma unroll
    for (int i = 0; i < 4; ++i) {
        int row = row0 + tr * 4 + i;
        if (row >= NN) break;
        float d = dis[row];
        __half2 h0 = __floats2half2_rn(acc[i].x * d, acc[i].y * d);
        __half2 h1 = __floats2half2_rn(acc[i].z * d, acc[i].w * d);
        uint2 st;
        st.x = *reinterpret_cast<unsigned int*>(&h0);
        st.y = *reinterpret_cast<unsigned int*>(&h1);
        *reinterpret_cast<uint2*>(&Ah[(size_t)row * DD + tc * 4]) = st;
    }
}

// ---------------- gather: B[c] = dis[c] * (A'[c] + sum_e w_e * A'[r_e]), fp16 out ----
__global__ __launch_bounds__(256) void gather_k(
    const int2* __restrict__ rowse, const unsigned int* __restrict__ srt,
    const float* __restrict__ dis,
    const __half2* __restrict__ Ah2, __half* __restrict__ Bh)
{
    const int node = blockIdx.x * 4 + (threadIdx.x >> 6);
    const int wl = threadIdx.x & 63;
    const int h = wl >> 5;     // which half of each 8-edge block
    const int l = wl & 31;     // feature-pair index
    if (node >= NN) return;
    const int2 se = rowse[node];
    float ax0 = 0.f, ay0 = 0.f, ax1 = 0.f, ay1 = 0.f;
    if (h == 0) {              // self-loop term on half 0
        __half2 s = Ah2[(size_t)node * 32 + l];
        ax0 = __half2float(__low2half(s));
        ay0 = __half2float(__high2half(s));
    }
    const unsigned int* p = srt + se.x + h * 4;
    for (int n = se.y; n > 0; n -= 8, p += 8) {
        uint4 u = *reinterpret_cast<const uint4*>(p);   // this half's 4 edges
        __half2 a0 = Ah2[(size_t)(u.x & 0xffffu) * 32 + l];
        __half2 a1 = Ah2[(size_t)(u.y & 0xffffu) * 32 + l];
        __half2 a2 = Ah2[(size_t)(u.z & 0xffffu) * 32 + l];
        __half2 a3 = Ah2[(size_t)(u.w & 0xffffu) * 32 + l];
        float w0 = __half2float(__ushort_as_half((unsigned short)(u.x >> 16)));
        float w1 = __half2float(__ushort_as_half((unsigned short)(u.y >> 16)));
        float w2 = __half2float(__ushort_as_half((unsigned short)(u.z >> 16)));
        float w3 = __half2float(__ushort_as_half((unsigned short)(u.w >> 16)));
        ax0 += w0 * __half2float(__low2half(a0));
        ay0 += w0 * __half2float(__high2half(a0));
        ax1 += w1 * __half2float(__low2half(a1));
        ay1 += w1 * __half2float(__high2half(a1));
        ax0 += w2 * __half2float(__low2half(a2));
        ay0 += w2 * __half2float(__high2half(a2));
        ax1 += w3 * __half2float(__low2half(a3));
        ay1 += w3 * __half2float(__high2half(a3));
    }
    float ax = ax0 + ax1, ay = ay0 + ay1;
    ax += __shfl_xor(ax, 32);
    ay += __shfl_xor(ay, 32);
    if (h == 0) {
        float d = dis[node];
        __half2 hv = __floats2half2_rn(d * ax, d * ay);
        *reinterpret_cast<__half2*>(&Bh[(size_t)node * DD + 2 * l]) = hv;
    }
}

// ---------------- pooling: 32 rows per block, fp16 input ----------------
__global__ __launch_bounds__(64) void pool(
    const __half* __restrict__ Bh, const float* __restrict__ b2,
    const int* __restrict__ batch,
    float* __restrict__ sums, float* __restrict__ cnts, int n)
{
    const int lane = threadIdx.x;
    const int start = blockIdx.x * 32;
    const int end = min(start + 32, n);
    const float bb = b2[lane];
    float acc = 0.0f;
    int cn = 0;
    int curg = batch[start];
    for (int i = start; i < end; ++i) {
        int g = batch[i];
        if (g != curg) {
            unsafeAtomicAdd(&sums[curg * DD + lane], acc);
            if (lane == 0) unsafeAtomicAdd(&cnts[curg], (float)cn);
            acc = 0.0f; cn = 0; curg = g;
        }
        acc += fmaxf(__half2float(Bh[(size_t)i * DD + lane]) + bb, 0.0f);
        cn++;
    }
    if (cn > 0) {
        unsafeAtomicAdd(&sums[curg * DD + lane], acc);
        if (lane == 0) unsafeAtomicAdd(&cnts[curg], (float)cn);
    }
}

__global__ void finalize(const float* __restrict__ sums, const float* __restrict__ cnts,
                         float* __restrict__ out) {
    int i = blockIdx.x * blockDim.x + threadIdx.x;
    if (i < NG * DD) {
        int g = i >> 6;
        out[i] = sums[i] / fmaxf(cnts[g], 1.0f);
    }
}

// ---------------- host ----------------
extern "C" void kernel_launch(void* const* d_in, const int* in_sizes, int n_in,
                              void* d_out, int out_size, void* d_ws, size_t ws_size,
                              hipStream_t stream) {
    const float* x   = (const float*)d_in[0];
    const int*   ei  = (const int*)  d_in[1];
    const float* ew  = (const float*)d_in[2];
    const int*   bat = (const int*)  d_in[3];
    const float* W1  = (const float*)d_in[4];
    const float* b1  = (const float*)d_in[5];
    const float* W2  = (const float*)d_in[6];
    const float* b2  = (const float*)d_in[7];
    float* out = (float*)d_out;

    char* ws = (char*)d_ws;
    size_t off = 0;
    __half* Ah        = (__half*)(ws + off); off += (size_t)NN * DD * 2;            // 6.4 MB
    __half* Bh        = (__half*)(ws + off); off += (size_t)NN * DD * 2;            // 6.4 MB
    unsigned int* srt = (unsigned int*)(ws + off); off += (size_t)NBKT * 4 * SRTQ * 4; // 5.6 MB
    unsigned int* tmp_pay = (unsigned int*)(ws + off); off += (size_t)NBKT * MAXB * 4;  // 4.0 MB
    unsigned char* tmp_c8 = (unsigned char*)(ws + off); off += (size_t)NBKT * MAXB;     // 1.0 MB
    int2*   rowse      = (int2*)(ws + off); off += (size_t)NN * 8;
    float*  dis        = (float*)(ws + off); off += (size_t)NN * 4;
    // contiguous zero-init region: bucket_cnt | sums | cnts
    int*    bucket_cnt = (int*)  (ws + off); off += (size_t)NBKT * 4;
    float*  sums       = (float*)(ws + off); off += (size_t)NG * DD * 4;
    float*  cnts       = (float*)(ws + off); off += (size_t)NG * 4;

    (void)hipMemsetAsync(bucket_cnt, 0, (size_t)(NBKT + NG * DD + NG) * 4, stream);

    // CSR build (shared by both layers) — no per-edge global atomics
    bin_k<<<P1NB, 256, 0, stream>>>(ei, ew, bucket_cnt, tmp_pay, tmp_c8);
    build_k<<<NBKT * 4, 256, 0, stream>>>(bucket_cnt, tmp_pay, tmp_c8, srt, rowse, dis);

    // layer 1
    gemm_k<false, float><<<(NN + 63) / 64, 256, 0, stream>>>(x, W1, nullptr, dis, Ah);
    gather_k<<<(NN + 3) / 4, 256, 0, stream>>>(rowse, srt, dis, (const __half2*)Ah, Bh);

    // layer 2
    gemm_k<true, __half><<<(NN + 63) / 64, 256, 0, stream>>>(Bh, W2, b1, dis, Ah);
    gather_k<<<(NN + 3) / 4, 256, 0, stream>>>(rowse, srt, dis, (const __half2*)Ah, Bh);

    // pooling (bias+relu fused on read)
    pool<<<(NN + 31) / 32, 64, 0, stream>>>(Bh, b2, bat, sums, cnts, NN);
    finalize<<<(NG * DD + 255) / 256, 256, 0, stream>>>(sums, cnts, out);
}

// Round 17
// 139.197 us; speedup vs baseline: 1.0372x; 1.0311x over previous
//
#include <hip/hip_runtime.h>
#include <hip/hip_fp16.h>

#define NN 50000
#define NE 800000
#define DD 64
#define NG 64

#define NBKT 196        // ceil(NN/256) coarse buckets (dst >> 8)
#define MAXB 5120       // padded tmp slots per bucket (mean 4082)
#define SRTB 7168       // srt slots per bucket (>= MAXB + 256*7 pad worst case)
#define P1CH 2048       // edges per pass-1 block
#define P1NB ((NE + P1CH - 1) / P1CH)   // 391

// ---------------- pass 1: bin edges by dst>>8 into padded tmp buckets ----------------
__global__ __launch_bounds__(256) void bin_k(const int* __restrict__ ei,
                                             const float* __restrict__ ew,
                                             int* __restrict__ bucket_cnt,
                                             unsigned int* __restrict__ tmp_pay,
                                             unsigned char* __restrict__ tmp_c8) {
    __shared__ int hist[NBKT];
    __shared__ int basec[NBKT];
    const int t = threadIdx.x;
    const int e0 = blockIdx.x * P1CH;
    for (int i = t; i < NBKT; i += 256) hist[i] = 0;
    __syncthreads();
    int rr[8]; int cc[8]; float wwf[8];
    #pragma unroll
    for (int i = 0; i < 8; ++i) {
        int e = e0 + i * 256 + t;
        if (e < NE) {
            rr[i] = ei[e]; cc[i] = ei[NE + e]; wwf[i] = ew[e];
            atomicAdd(&hist[cc[i] >> 8], 1);
        } else cc[i] = -1;
    }
    __syncthreads();
    for (int i = t; i < NBKT; i += 256)
        basec[i] = (hist[i] > 0) ? (i * MAXB + atomicAdd(&bucket_cnt[i], hist[i])) : 0;
    __syncthreads();
    #pragma unroll
    for (int i = 0; i < 8; ++i) {
        if (cc[i] >= 0) {
            int b = cc[i] >> 8;
            int slot = atomicAdd(&basec[b], 1);   // LDS cursor within reservation
            unsigned int hb = (unsigned int)__half_as_ushort(__float2half(wwf[i]));
            tmp_pay[slot] = (hb << 16) | (unsigned int)rr[i];
            tmp_c8[slot] = (unsigned char)(cc[i] & 255);
        }
    }
}

// ---------------- pass 2: per-bucket exact sort + per-node (start,pcnt) + dis ----------
__global__ __launch_bounds__(256) void build_k(const int* __restrict__ bucket_cnt,
                                               const unsigned int* __restrict__ tmp_pay,
                                               const unsigned char* __restrict__ tmp_c8,
                                               unsigned int* __restrict__ srt,
                                               int2* __restrict__ rowse,
                                               float* __restrict__ dis) {
    __shared__ int hist[256];
    __shared__ int cursor[256];
    __shared__ float degf[256];
    __shared__ int wtot[4];
    const int b = blockIdx.x;
    const int t = threadIdx.x;
    const int cntb = bucket_cnt[b];
    const int tbase = b * MAXB;
    hist[t] = 0; degf[t] = 0.0f;
    __syncthreads();
    for (int i = t; i < cntb; i += 256) atomicAdd(&hist[tmp_c8[tbase + i]], 1);
    __syncthreads();
    const int v = hist[t];
    const int pv = (v + 7) & ~7;
    int pre = pv;
    #pragma unroll
    for (int off = 1; off < 64; off <<= 1) {
        int u = __shfl_up(pre, off);
        if ((t & 63) >= off) pre += u;
    }
    if ((t & 63) == 63) wtot[t >> 6] = pre;
    __syncthreads();
    int woff = 0;
    for (int i = 0; i < (t >> 6); ++i) woff += wtot[i];
    const int start = b * SRTB + woff + pre - pv;
    cursor[t] = start;
    __syncthreads();
    for (int i = t; i < cntb; i += 256) {
        unsigned int u = tmp_pay[tbase + i];
        int c8 = tmp_c8[tbase + i];
        int slot = atomicAdd(&cursor[c8], 1);   // LDS
        srt[slot] = u;
        float w = __half2float(__ushort_as_half((unsigned short)(u >> 16)));
        atomicAdd(&degf[c8], w);                // LDS fp32
    }
    __syncthreads();
    for (int i = start + v; i < start + pv; ++i) srt[i] = 0u;
    const int node = b * 256 + t;
    if (node < NN) {
        rowse[node] = make_int2(start, pv);
        dis[node] = rsqrtf(1.0f + degf[t]);
    }
}

// ---------------- GEMM: A' = (act(X) @ W) * dis[row], fp16 out ----------------
template<bool ACT>
__global__ __launch_bounds__(256, 4) void gemm_k(
    const float* __restrict__ X, const float* __restrict__ W,
    const float* __restrict__ bias_prev, const float* __restrict__ dis,
    __half* __restrict__ Ah)
{
    __shared__ float Ws[64][64];   // [k][j]
    __shared__ float Xs[64][68];   // [r][k], +4 pad
    const int t = threadIdx.x;
    const int row0 = blockIdx.x * 64;

    #pragma unroll
    for (int s = t; s < 64 * 64; s += 256) ((float*)Ws)[s] = W[s];
    #pragma unroll
    for (int s = t; s < 64 * 64; s += 256) {
        int r = s >> 6, k = s & 63;
        int row = row0 + r;
        if (row >= NN) row = NN - 1;
        float v = X[(size_t)row * DD + k];
        if (ACT) v = fmaxf(v + bias_prev[k], 0.0f);
        Xs[r][k] = v;
    }
    __syncthreads();

    const int tc = t & 15;
    const int tr = t >> 4;
    float4 acc[4];
    #pragma unroll
    for (int i = 0; i < 4; ++i) acc[i] = make_float4(0.f, 0.f, 0.f, 0.f);

    #pragma unroll 2
    for (int kc = 0; kc < 16; ++kc) {
        const int k = kc * 4;
        float4 w0 = *reinterpret_cast<const float4*>(&Ws[k + 0][tc * 4]);
        float4 w1 = *reinterpret_cast<const float4*>(&Ws[k + 1][tc * 4]);
        float4 w2 = *reinterpret_cast<const float4*>(&Ws[k + 2][tc * 4]);
        float4 w3 = *reinterpret_cast<const float4*>(&Ws[k + 3][tc * 4]);
        #pragma unroll
        for (int i = 0; i < 4; ++i) {
            float4 xv = *reinterpret_cast<const float4*>(&Xs[tr * 4 + i][k]);
            acc[i].x += xv.x * w0.x + xv.y * w1.x + xv.z * w2.x + xv.w * w3.x;
            acc[i].y += xv.x * w0.y + xv.y * w1.y + xv.z * w2.y + xv.w * w3.y;
            acc[i].z += xv.x * w0.z + xv.y * w1.z + xv.z * w2.z + xv.w * w3.z;
            acc[i].w += xv.x * w0.w + xv.y * w1.w + xv.z * w2.w + xv.w * w3.w;
        }
    }

    #pragma unroll
    for (int i = 0; i < 4; ++i) {
        int row = row0 + tr * 4 + i;
        if (row >= NN) break;
        float d = dis[row];
        __half2 h0 = __floats2half2_rn(acc[i].x * d, acc[i].y * d);
        __half2 h1 = __floats2half2_rn(acc[i].z * d, acc[i].w * d);
        uint2 st;
        st.x = *reinterpret_cast<unsigned int*>(&h0);
        st.y = *reinterpret_cast<unsigned int*>(&h1);
        *reinterpret_cast<uint2*>(&Ah[(size_t)row * DD + tc * 4]) = st;
    }
}

// ---------------- gather: B[c] = dis[c] * (A'[c] + sum_e w_e * A'[r_e]) ----------------
// One wave per node; halves split the edge stream (h0: edges 0-3 of each 8-block,
// h1: edges 4-7). Each lane loads __half2 (2 features) -> one VMEM instruction
// covers TWO rows; 8 rows in flight per wave with half the instructions.
__global__ __launch_bounds__(256) void gather_k(
    const int2* __restrict__ rowse, const unsigned int* __restrict__ srt,
    const float* __restrict__ dis,
    const __half2* __restrict__ Ah2, float* __restrict__ B)
{
    const int node = blockIdx.x * 4 + (threadIdx.x >> 6);
    const int wl = threadIdx.x & 63;
    const int h = wl >> 5;     // which half of each 8-edge block
    const int l = wl & 31;     // feature-pair index
    if (node >= NN) return;
    const int2 se = rowse[node];
    float ax0 = 0.f, ay0 = 0.f, ax1 = 0.f, ay1 = 0.f;
    if (h == 0) {              // self-loop term on half 0
        __half2 s = Ah2[(size_t)node * 32 + l];
        ax0 = __half2float(__low2half(s));
        ay0 = __half2float(__high2half(s));
    }
    const unsigned int* p = srt + se.x + h * 4;
    for (int n = se.y; n > 0; n -= 8, p += 8) {
        uint4 u = *reinterpret_cast<const uint4*>(p);   // this half's 4 edges
        __half2 a0 = Ah2[(size_t)(u.x & 0xffffu) * 32 + l];
        __half2 a1 = Ah2[(size_t)(u.y & 0xffffu) * 32 + l];
        __half2 a2 = Ah2[(size_t)(u.z & 0xffffu) * 32 + l];
        __half2 a3 = Ah2[(size_t)(u.w & 0xffffu) * 32 + l];
        float w0 = __half2float(__ushort_as_half((unsigned short)(u.x >> 16)));
        float w1 = __half2float(__ushort_as_half((unsigned short)(u.y >> 16)));
        float w2 = __half2float(__ushort_as_half((unsigned short)(u.z >> 16)));
        float w3 = __half2float(__ushort_as_half((unsigned short)(u.w >> 16)));
        ax0 += w0 * __half2float(__low2half(a0));
        ay0 += w0 * __half2float(__high2half(a0));
        ax1 += w1 * __half2float(__low2half(a1));
        ay1 += w1 * __half2float(__high2half(a1));
        ax0 += w2 * __half2float(__low2half(a2));
        ay0 += w2 * __half2float(__high2half(a2));
        ax1 += w3 * __half2float(__low2half(a3));
        ay1 += w3 * __half2float(__high2half(a3));
    }
    float ax = ax0 + ax1, ay = ay0 + ay1;
    ax += __shfl_xor(ax, 32);
    ay += __shfl_xor(ay, 32);
    if (h == 0) {
        float d = dis[node];
        *reinterpret_cast<float2*>(&B[(size_t)node * DD + 2 * l]) =
            make_float2(d * ax, d * ay);
    }
}

// ---------------- pooling: 32 rows per block ----------------
__global__ __launch_bounds__(64) void pool(
    const float* __restrict__ B, const float* __restrict__ b2,
    const int* __restrict__ batch,
    float* __restrict__ sums, float* __restrict__ cnts, int n)
{
    const int lane = threadIdx.x;
    const int start = blockIdx.x * 32;
    const int end = min(start + 32, n);
    const float bb = b2[lane];
    float acc = 0.0f;
    int cn = 0;
    int curg = batch[start];
    for (int i = start; i < end; ++i) {
        int g = batch[i];
        if (g != curg) {
            unsafeAtomicAdd(&sums[curg * DD + lane], acc);
            if (lane == 0) unsafeAtomicAdd(&cnts[curg], (float)cn);
            acc = 0.0f; cn = 0; curg = g;
        }
        acc += fmaxf(B[(size_t)i * DD + lane] + bb, 0.0f);
        cn++;
    }
    if (cn > 0) {
        unsafeAtomicAdd(&sums[curg * DD + lane], acc);
        if (lane == 0) unsafeAtomicAdd(&cnts[curg], (float)cn);
    }
}

__global__ void finalize(const float* __restrict__ sums, const float* __restrict__ cnts,
                         float* __restrict__ out) {
    int i = blockIdx.x * blockDim.x + threadIdx.x;
    if (i < NG * DD) {
        int g = i >> 6;
        out[i] = sums[i] / fmaxf(cnts[g], 1.0f);
    }
}

// ---------------- host ----------------
extern "C" void kernel_launch(void* const* d_in, const int* in_sizes, int n_in,
                              void* d_out, int out_size, void* d_ws, size_t ws_size,
                              hipStream_t stream) {
    const float* x   = (const float*)d_in[0];
    const int*   ei  = (const int*)  d_in[1];
    const float* ew  = (const float*)d_in[2];
    const int*   bat = (const int*)  d_in[3];
    const float* W1  = (const float*)d_in[4];
    const float* b1  = (const float*)d_in[5];
    const float* W2  = (const float*)d_in[6];
    const float* b2  = (const float*)d_in[7];
    float* out = (float*)d_out;

    char* ws = (char*)d_ws;
    size_t off = 0;
    __half* Ah        = (__half*)(ws + off); off += (size_t)NN * DD * 2;          // 6.4 MB
    float*  B         = (float*) (ws + off); off += (size_t)NN * DD * 4;          // 12.8 MB
    unsigned int* srt = (unsigned int*)(ws + off); off += (size_t)NBKT * SRTB * 4; // 5.6 MB
    unsigned int* tmp_pay = (unsigned int*)(ws + off); off += (size_t)NBKT * MAXB * 4;  // 4.0 MB
    unsigned char* tmp_c8 = (unsigned char*)(ws + off); off += (size_t)NBKT * MAXB;     // 1.0 MB
    int2*   rowse      = (int2*)(ws + off); off += (size_t)NN * 8;
    float*  dis        = (float*)(ws + off); off += (size_t)NN * 4;
    // contiguous zero-init region: bucket_cnt | sums | cnts
    int*    bucket_cnt = (int*)  (ws + off); off += (size_t)NBKT * 4;
    float*  sums       = (float*)(ws + off); off += (size_t)NG * DD * 4;
    float*  cnts       = (float*)(ws + off); off += (size_t)NG * 4;

    (void)hipMemsetAsync(bucket_cnt, 0, (size_t)(NBKT + NG * DD + NG) * 4, stream);

    // CSR build (shared by both layers) — no per-edge global atomics
    bin_k<<<P1NB, 256, 0, stream>>>(ei, ew, bucket_cnt, tmp_pay, tmp_c8);
    build_k<<<NBKT, 256, 0, stream>>>(bucket_cnt, tmp_pay, tmp_c8, srt, rowse, dis);

    // layer 1
    gemm_k<false><<<(NN + 63) / 64, 256, 0, stream>>>(x, W1, nullptr, dis, Ah);
    gather_k<<<(NN + 3) / 4, 256, 0, stream>>>(rowse, srt, dis, (const __half2*)Ah, B);

    // layer 2
    gemm_k<true><<<(NN + 63) / 64, 256, 0, stream>>>(B, W2, b1, dis, Ah);
    gather_k<<<(NN + 3) / 4, 256, 0, stream>>>(rowse, srt, dis, (const __half2*)Ah, B);

    // pooling (bias+relu fused on read)
    pool<<<(NN + 31) / 32, 64, 0, stream>>>(B, b2, bat, sums, cnts, NN);
    finalize<<<(NG * DD + 255) / 256, 256, 0, stream>>>(sums, cnts, out);
}

// Round 18
// 135.562 us; speedup vs baseline: 1.0650x; 1.0268x over previous
//
#include <hip/hip_runtime.h>
#include <hip/hip_fp16.h>

#define NN 50000
#define NE 800000
#define DD 64
#define NG 64

#define NBKT 196        // ceil(NN/256) coarse buckets (dst >> 8)
#define MAXB 5120       // padded tmp slots per bucket (mean 4082)
#define SRTB 9216       // srt slots per bucket (>= MAXB + 256*15 pad worst case)
#define P1CH 2048       // edges per pass-1 block
#define P1NB ((NE + P1CH - 1) / P1CH)   // 391

// ---------------- pass 1: bin edges by dst>>8 into padded tmp buckets ----------------
__global__ __launch_bounds__(256) void bin_k(const int* __restrict__ ei,
                                             const float* __restrict__ ew,
                                             int* __restrict__ bucket_cnt,
                                             unsigned int* __restrict__ tmp_pay,
                                             unsigned char* __restrict__ tmp_c8) {
    __shared__ int hist[NBKT];
    __shared__ int basec[NBKT];
    const int t = threadIdx.x;
    const int e0 = blockIdx.x * P1CH;
    for (int i = t; i < NBKT; i += 256) hist[i] = 0;
    __syncthreads();
    int rr[8]; int cc[8]; float wwf[8];
    #pragma unroll
    for (int i = 0; i < 8; ++i) {
        int e = e0 + i * 256 + t;
        if (e < NE) {
            rr[i] = ei[e]; cc[i] = ei[NE + e]; wwf[i] = ew[e];
            atomicAdd(&hist[cc[i] >> 8], 1);
        } else cc[i] = -1;
    }
    __syncthreads();
    for (int i = t; i < NBKT; i += 256)
        basec[i] = (hist[i] > 0) ? (i * MAXB + atomicAdd(&bucket_cnt[i], hist[i])) : 0;
    __syncthreads();
    #pragma unroll
    for (int i = 0; i < 8; ++i) {
        if (cc[i] >= 0) {
            int b = cc[i] >> 8;
            int slot = atomicAdd(&basec[b], 1);   // LDS cursor within reservation
            unsigned int hb = (unsigned int)__half_as_ushort(__float2half(wwf[i]));
            tmp_pay[slot] = (hb << 16) | (unsigned int)rr[i];
            tmp_c8[slot] = (unsigned char)(cc[i] & 255);
        }
    }
}

// ---------------- pass 2: per-bucket exact sort + per-node (start,pcnt) + dis ----------
// Segments padded to multiple of 16 with (r=0,w=0) dummy edges.
__global__ __launch_bounds__(256) void build_k(const int* __restrict__ bucket_cnt,
                                               const unsigned int* __restrict__ tmp_pay,
                                               const unsigned char* __restrict__ tmp_c8,
                                               unsigned int* __restrict__ srt,
                                               int2* __restrict__ rowse,
                                               float* __restrict__ dis) {
    __shared__ int hist[256];
    __shared__ int cursor[256];
    __shared__ float degf[256];
    __shared__ int wtot[4];
    const int b = blockIdx.x;
    const int t = threadIdx.x;
    const int cntb = bucket_cnt[b];
    const int tbase = b * MAXB;
    hist[t] = 0; degf[t] = 0.0f;
    __syncthreads();
    for (int i = t; i < cntb; i += 256) atomicAdd(&hist[tmp_c8[tbase + i]], 1);
    __syncthreads();
    const int v = hist[t];
    const int pv = (v + 15) & ~15;
    int pre = pv;
    #pragma unroll
    for (int off = 1; off < 64; off <<= 1) {
        int u = __shfl_up(pre, off);
        if ((t & 63) >= off) pre += u;
    }
    if ((t & 63) == 63) wtot[t >> 6] = pre;
    __syncthreads();
    int woff = 0;
    for (int i = 0; i < (t >> 6); ++i) woff += wtot[i];
    const int start = b * SRTB + woff + pre - pv;
    cursor[t] = start;
    __syncthreads();
    for (int i = t; i < cntb; i += 256) {
        unsigned int u = tmp_pay[tbase + i];
        int c8 = tmp_c8[tbase + i];
        int slot = atomicAdd(&cursor[c8], 1);   // LDS
        srt[slot] = u;
        float w = __half2float(__ushort_as_half((unsigned short)(u >> 16)));
        atomicAdd(&degf[c8], w);                // LDS fp32
    }
    __syncthreads();
    for (int i = start + v; i < start + pv; ++i) srt[i] = 0u;
    const int node = b * 256 + t;
    if (node < NN) {
        rowse[node] = make_int2(start, pv);
        dis[node] = rsqrtf(1.0f + degf[t]);
    }
}

// ---------------- GEMM: A' = (act(X) @ W) * dis[row], fp16 out ----------------
template<bool ACT>
__global__ __launch_bounds__(256, 4) void gemm_k(
    const float* __restrict__ X, const float* __restrict__ W,
    const float* __restrict__ bias_prev, const float* __restrict__ dis,
    __half* __restrict__ Ah)
{
    __shared__ float Ws[64][64];   // [k][j]
    __shared__ float Xs[64][68];   // [r][k], +4 pad
    const int t = threadIdx.x;
    const int row0 = blockIdx.x * 64;

    #pragma unroll
    for (int s = t; s < 64 * 64; s += 256) ((float*)Ws)[s] = W[s];
    #pragma unroll
    for (int s = t; s < 64 * 64; s += 256) {
        int r = s >> 6, k = s & 63;
        int row = row0 + r;
        if (row >= NN) row = NN - 1;
        float v = X[(size_t)row * DD + k];
        if (ACT) v = fmaxf(v + bias_prev[k], 0.0f);
        Xs[r][k] = v;
    }
    __syncthreads();

    const int tc = t & 15;
    const int tr = t >> 4;
    float4 acc[4];
    #pragma unroll
    for (int i = 0; i < 4; ++i) acc[i] = make_float4(0.f, 0.f, 0.f, 0.f);

    #pragma unroll 2
    for (int kc = 0; kc < 16; ++kc) {
        const int k = kc * 4;
        float4 w0 = *reinterpret_cast<const float4*>(&Ws[k + 0][tc * 4]);
        float4 w1 = *reinterpret_cast<const float4*>(&Ws[k + 1][tc * 4]);
        float4 w2 = *reinterpret_cast<const float4*>(&Ws[k + 2][tc * 4]);
        float4 w3 = *reinterpret_cast<const float4*>(&Ws[k + 3][tc * 4]);
        #pragma unroll
        for (int i = 0; i < 4; ++i) {
            float4 xv = *reinterpret_cast<const float4*>(&Xs[tr * 4 + i][k]);
            acc[i].x += xv.x * w0.x + xv.y * w1.x + xv.z * w2.x + xv.w * w3.x;
            acc[i].y += xv.x * w0.y + xv.y * w1.y + xv.z * w2.y + xv.w * w3.y;
            acc[i].z += xv.x * w0.z + xv.y * w1.z + xv.z * w2.z + xv.w * w3.z;
            acc[i].w += xv.x * w0.w + xv.y * w1.w + xv.z * w2.w + xv.w * w3.w;
        }
    }

    #pragma unroll
    for (int i = 0; i < 4; ++i) {
        int row = row0 + tr * 4 + i;
        if (row >= NN) break;
        float d = dis[row];
        __half2 h0 = __floats2half2_rn(acc[i].x * d, acc[i].y * d);
        __half2 h1 = __floats2half2_rn(acc[i].z * d, acc[i].w * d);
        uint2 st;
        st.x = *reinterpret_cast<unsigned int*>(&h0);
        st.y = *reinterpret_cast<unsigned int*>(&h1);
        *reinterpret_cast<uint2*>(&Ah[(size_t)row * DD + tc * 4]) = st;
    }
}

// ---------------- gather: B[c] = dis[c] * (A'[c] + sum_e w_e * A'[r_e]) ----------------
// One wave per node; QUARTER-waves split the edge stream 4 ways. Each lane loads
// uint2 (4 features, 8 B) -> one wave-wide VMEM instruction covers FOUR rows;
// 16 rows in flight per wave, 0.31 VMEM instr/edge.
__global__ __launch_bounds__(256) void gather_k(
    const int2* __restrict__ rowse, const unsigned int* __restrict__ srt,
    const float* __restrict__ dis,
    const uint2* __restrict__ Ah4,      // [NN][16] uint2-view of Ah
    float* __restrict__ B)
{
    const int node = blockIdx.x * 4 + (threadIdx.x >> 6);
    const int wl = threadIdx.x & 63;
    const int q = wl >> 4;     // quarter 0..3: handles edge slots 4q..4q+3
    const int l = wl & 15;     // feature-quad index (features 4l..4l+3)
    if (node >= NN) return;
    const int2 se = rowse[node];
    float4 acc = make_float4(0.f, 0.f, 0.f, 0.f);
    if (q == 0) {              // self-loop term once
        uint2 s = Ah4[(size_t)node * 16 + l];
        __half2 s01 = *reinterpret_cast<const __half2*>(&s.x);
        __half2 s23 = *reinterpret_cast<const __half2*>(&s.y);
        acc.x = __half2float(__low2half(s01));
        acc.y = __half2float(__high2half(s01));
        acc.z = __half2float(__low2half(s23));
        acc.w = __half2float(__high2half(s23));
    }
    const unsigned int* base = srt + se.x + 4 * q;
    for (int n = se.y; n > 0; n -= 16, base += 16) {
        uint4 u = *reinterpret_cast<const uint4*>(base);   // this quarter's 4 edges
        uint2 r0 = Ah4[(size_t)(u.x & 0xffffu) * 16 + l];
        uint2 r1 = Ah4[(size_t)(u.y & 0xffffu) * 16 + l];
        uint2 r2 = Ah4[(size_t)(u.z & 0xffffu) * 16 + l];
        uint2 r3 = Ah4[(size_t)(u.w & 0xffffu) * 16 + l];
        float w0 = __half2float(__ushort_as_half((unsigned short)(u.x >> 16)));
        float w1 = __half2float(__ushort_as_half((unsigned short)(u.y >> 16)));
        float w2 = __half2float(__ushort_as_half((unsigned short)(u.z >> 16)));
        float w3 = __half2float(__ushort_as_half((unsigned short)(u.w >> 16)));
        {
            __half2 a01 = *reinterpret_cast<const __half2*>(&r0.x);
            __half2 a23 = *reinterpret_cast<const __half2*>(&r0.y);
            acc.x += w0 * __half2float(__low2half(a01));
            acc.y += w0 * __half2float(__high2half(a01));
            acc.z += w0 * __half2float(__low2half(a23));
            acc.w += w0 * __half2float(__high2half(a23));
        }
        {
            __half2 a01 = *reinterpret_cast<const __half2*>(&r1.x);
            __half2 a23 = *reinterpret_cast<const __half2*>(&r1.y);
            acc.x += w1 * __half2float(__low2half(a01));
            acc.y += w1 * __half2float(__high2half(a01));
            acc.z += w1 * __half2float(__low2half(a23));
            acc.w += w1 * __half2float(__high2half(a23));
        }
        {
            __half2 a01 = *reinterpret_cast<const __half2*>(&r2.x);
            __half2 a23 = *reinterpret_cast<const __half2*>(&r2.y);
            acc.x += w2 * __half2float(__low2half(a01));
            acc.y += w2 * __half2float(__high2half(a01));
            acc.z += w2 * __half2float(__low2half(a23));
            acc.w += w2 * __half2float(__high2half(a23));
        }
        {
            __half2 a01 = *reinterpret_cast<const __half2*>(&r3.x);
            __half2 a23 = *reinterpret_cast<const __half2*>(&r3.y);
            acc.x += w3 * __half2float(__low2half(a01));
            acc.y += w3 * __half2float(__high2half(a01));
            acc.z += w3 * __half2float(__low2half(a23));
            acc.w += w3 * __half2float(__high2half(a23));
        }
    }
    // reduce across the 4 quarters
    acc.x += __shfl_xor(acc.x, 16); acc.x += __shfl_xor(acc.x, 32);
    acc.y += __shfl_xor(acc.y, 16); acc.y += __shfl_xor(acc.y, 32);
    acc.z += __shfl_xor(acc.z, 16); acc.z += __shfl_xor(acc.z, 32);
    acc.w += __shfl_xor(acc.w, 16); acc.w += __shfl_xor(acc.w, 32);
    if (q == 0) {
        float d = dis[node];
        *reinterpret_cast<float4*>(&B[(size_t)node * DD + 4 * l]) =
            make_float4(d * acc.x, d * acc.y, d * acc.z, d * acc.w);
    }
}

// ---------------- pooling: 32 rows per block ----------------
__global__ __launch_bounds__(64) void pool(
    const float* __restrict__ B, const float* __restrict__ b2,
    const int* __restrict__ batch,
    float* __restrict__ sums, float* __restrict__ cnts, int n)
{
    const int lane = threadIdx.x;
    const int start = blockIdx.x * 32;
    const int end = min(start + 32, n);
    const float bb = b2[lane];
    float acc = 0.0f;
    int cn = 0;
    int curg = batch[start];
    for (int i = start; i < end; ++i) {
        int g = batch[i];
        if (g != curg) {
            unsafeAtomicAdd(&sums[curg * DD + lane], acc);
            if (lane == 0) unsafeAtomicAdd(&cnts[curg], (float)cn);
            acc = 0.0f; cn = 0; curg = g;
        }
        acc += fmaxf(B[(size_t)i * DD + lane] + bb, 0.0f);
        cn++;
    }
    if (cn > 0) {
        unsafeAtomicAdd(&sums[curg * DD + lane], acc);
        if (lane == 0) unsafeAtomicAdd(&cnts[curg], (float)cn);
    }
}

__global__ void finalize(const float* __restrict__ sums, const float* __restrict__ cnts,
                         float* __restrict__ out) {
    int i = blockIdx.x * blockDim.x + threadIdx.x;
    if (i < NG * DD) {
        int g = i >> 6;
        out[i] = sums[i] / fmaxf(cnts[g], 1.0f);
    }
}

// ---------------- host ----------------
extern "C" void kernel_launch(void* const* d_in, const int* in_sizes, int n_in,
                              void* d_out, int out_size, void* d_ws, size_t ws_size,
                              hipStream_t stream) {
    const float* x   = (const float*)d_in[0];
    const int*   ei  = (const int*)  d_in[1];
    const float* ew  = (const float*)d_in[2];
    const int*   bat = (const int*)  d_in[3];
    const float* W1  = (const float*)d_in[4];
    const float* b1  = (const float*)d_in[5];
    const float* W2  = (const float*)d_in[6];
    const float* b2  = (const float*)d_in[7];
    float* out = (float*)d_out;

    char* ws = (char*)d_ws;
    size_t off = 0;
    __half* Ah        = (__half*)(ws + off); off += (size_t)NN * DD * 2;          // 6.4 MB
    float*  B         = (float*) (ws + off); off += (size_t)NN * DD * 4;          // 12.8 MB
    unsigned int* srt = (unsigned int*)(ws + off); off += (size_t)NBKT * SRTB * 4; // 7.2 MB
    unsigned int* tmp_pay = (unsigned int*)(ws + off); off += (size_t)NBKT * MAXB * 4;  // 4.0 MB
    unsigned char* tmp_c8 = (unsigned char*)(ws + off); off += (size_t)NBKT * MAXB;     // 1.0 MB
    int2*   rowse      = (int2*)(ws + off); off += (size_t)NN * 8;
    float*  dis        = (float*)(ws + off); off += (size_t)NN * 4;
    // contiguous zero-init region: bucket_cnt | sums | cnts
    int*    bucket_cnt = (int*)  (ws + off); off += (size_t)NBKT * 4;
    float*  sums       = (float*)(ws + off); off += (size_t)NG * DD * 4;
    float*  cnts       = (float*)(ws + off); off += (size_t)NG * 4;

    (void)hipMemsetAsync(bucket_cnt, 0, (size_t)(NBKT + NG * DD + NG) * 4, stream);

    // CSR build (shared by both layers) — no per-edge global atomics
    bin_k<<<P1NB, 256, 0, stream>>>(ei, ew, bucket_cnt, tmp_pay, tmp_c8);
    build_k<<<NBKT, 256, 0, stream>>>(bucket_cnt, tmp_pay, tmp_c8, srt, rowse, dis);

    // layer 1
    gemm_k<false><<<(NN + 63) / 64, 256, 0, stream>>>(x, W1, nullptr, dis, Ah);
    gather_k<<<(NN + 3) / 4, 256, 0, stream>>>(rowse, srt, dis, (const uint2*)Ah, B);

    // layer 2
    gemm_k<true><<<(NN + 63) / 64, 256, 0, stream>>>(B, W2, b1, dis, Ah);
    gather_k<<<(NN + 3) / 4, 256, 0, stream>>>(rowse, srt, dis, (const uint2*)Ah, B);

    // pooling (bias+relu fused on read)
    pool<<<(NN + 31) / 32, 64, 0, stream>>>(B, b2, bat, sums, cnts, NN);
    finalize<<<(NG * DD + 255) / 256, 256, 0, stream>>>(sums, cnts, out);
}